// Round 5
// baseline (335.721 us; speedup 1.0000x reference)
//
#include <hip/hip_runtime.h>

#define N_NODES 50000
#define N_EDGES 800000

typedef __attribute__((ext_vector_type(8))) short short8;
typedef __attribute__((ext_vector_type(4))) float floatx4;

// float -> bf16 bits, round-to-nearest-even
static __device__ __forceinline__ unsigned short f2b(float f) {
    unsigned int u = __float_as_uint(f);
    unsigned int r = u + 0x7fffu + ((u >> 16) & 1u);
    return (unsigned short)(r >> 16);
}
static __device__ __forceinline__ unsigned int pk(float a, float b) {
    return (unsigned)f2b(a) | ((unsigned)f2b(b) << 16);
}
// low/high bf16 of a packed uint -> float
static __device__ __forceinline__ float blo(unsigned int u) {
    return __uint_as_float(u << 16);
}
static __device__ __forceinline__ float bhi(unsigned int u) {
    return __uint_as_float(u & 0xffff0000u);
}

// ---------------------------------------------------------------------------
// CSR build: histogram -> 3-phase parallel exclusive scan -> fill.
// ---------------------------------------------------------------------------
__global__ void hist_kernel(const int* __restrict__ dst, int* __restrict__ deg,
                            int n) {
    int i = blockIdx.x * blockDim.x + threadIdx.x;
    if (i < n) atomicAdd(&deg[dst[i]], 1);
}

__global__ __launch_bounds__(1024) void scanA_kernel(
    const int* __restrict__ deg, int* __restrict__ bsum, int n) {
    __shared__ int s[1024];
    const int tid = threadIdx.x;
    int i = blockIdx.x * 1024 + tid;
    s[tid] = (i < n) ? deg[i] : 0;
    __syncthreads();
    for (int d = 512; d > 0; d >>= 1) {
        if (tid < d) s[tid] += s[tid + d];
        __syncthreads();
    }
    if (tid == 0) bsum[blockIdx.x] = s[0];
}

__global__ __launch_bounds__(64) void scanB_kernel(int* __restrict__ bsum,
                                                   int nb) {
    const int tid = threadIdx.x;
    int v = (tid < nb) ? bsum[tid] : 0;
    for (int d = 1; d < 64; d <<= 1) {
        int t = __shfl_up(v, d, 64);
        if (tid >= d) v += t;
    }
    int excl = __shfl_up(v, 1, 64);
    if (tid == 0) excl = 0;
    if (tid < nb) bsum[tid] = excl;
}

__global__ __launch_bounds__(1024) void scanC_kernel(
    const int* __restrict__ deg, const int* __restrict__ bpref,
    int* __restrict__ off, int* __restrict__ cursor, int n) {
    __shared__ int s[1024];
    const int tid = threadIdx.x;
    const int i = blockIdx.x * 1024 + tid;
    const int v = (i < n) ? deg[i] : 0;
    s[tid] = v;
    __syncthreads();
    for (int d = 1; d < 1024; d <<= 1) {
        int t = (tid >= d) ? s[tid - d] : 0;
        __syncthreads();
        s[tid] += t;
        __syncthreads();
    }
    const int excl = s[tid] - v + bpref[blockIdx.x];
    if (i < n) {
        off[i] = excl;
        cursor[i] = excl;
        if (i == n - 1) off[n] = excl + v;
    }
}

__global__ void fill_kernel(const int* __restrict__ src,
                            const int* __restrict__ dst,
                            int* __restrict__ cursor, int* __restrict__ nbr,
                            int n) {
    int i = blockIdx.x * blockDim.x + threadIdx.x;
    if (i < n) {
        int pos = atomicAdd(&cursor[dst[i]], 1);
        nbr[pos] = src[i];
    }
}

// ---------------------------------------------------------------------------
// Weight prep: transpose to [N][K] row-major and convert to bf16, so a
// B-fragment lane (col n = lane&15, k = quad*8+j) is one contiguous 16B load.
// ---------------------------------------------------------------------------
__global__ __launch_bounds__(256) void prep_weights_kernel(
    const float* __restrict__ W1a, const float* __restrict__ W1b,
    const float* __restrict__ W2a, const float* __restrict__ W2b,
    unsigned short* __restrict__ W1aT, unsigned short* __restrict__ W1bT,
    unsigned short* __restrict__ W2aT, unsigned short* __restrict__ W2bT) {
    int i = blockIdx.x * 256 + threadIdx.x;
    if (i < 8192) {                       // W1a [64][128] -> [128][64]
        int n = i >> 6, k = i & 63;
        W1aT[i] = f2b(W1a[k * 128 + n]);
    } else if (i < 24576) {               // W1b [128][128] -> [128][128]
        int j = i - 8192, n = j >> 7, k = j & 127;
        W1bT[j] = f2b(W1b[k * 128 + n]);
    } else if (i < 40960) {               // W2a [128][128] -> [128][128]
        int j = i - 24576, n = j >> 7, k = j & 127;
        W2aT[j] = f2b(W2a[k * 128 + n]);
    } else if (i < 49152) {               // W2b [128][64] -> [64][128]
        int j = i - 40960, n = j >> 7, k = j & 127;
        W2bT[j] = f2b(W2b[k * 64 + n]);
    }
}

// x fp32 [N][64] -> bf16 xb (halves gather1's random-row read traffic)
__global__ __launch_bounds__(256) void convert_x_kernel(
    const float* __restrict__ x, unsigned short* __restrict__ xb, int n4) {
    int i = blockIdx.x * 256 + threadIdx.x;
    if (i < n4) {
        float4 v = ((const float4*)x)[i];
        uint2 o;
        o.x = pk(v.x, v.y);
        o.y = pk(v.z, v.w);
        ((uint2*)xb)[i] = o;
    }
}

// ---------------------------------------------------------------------------
// Fused GIN layer: gather (t = x_i + sum_nbr x_j, fp32 accumulate) straight
// into the LDS A-tile, then 2-layer MLP via MFMA 16x16x32 bf16:
//   out = relu( relu(T @ Wa + ba) @ Wb + bb )
// Block = 256 thr (4 waves), 64 rows/block. Gather: 16 lanes/node, 4 node
// groups; each lane reads 8B (DIN=64) / 16B (DIN=128) bf16 per neighbor row
// (rows L2/LLC-resident), packs bf16 into padded LDS rows.
// A frags: contiguous 16B ds_read_b128 (rows padded +16 bf16).
// B frags: contiguous 16B global loads from [N][K] bf16 weights (L1-cached).
// C/D layout: col=lane&15, row=quad*4+reg. Phase1 hidden tile -> LDS; each
// wave reads back only its own 16-row strip, so no barrier between phases.
// ---------------------------------------------------------------------------
template <int DIN, int DH, int DOUT, bool OUT_BF16>
__global__ __launch_bounds__(256) void gin_fused_kernel(
    const unsigned short* __restrict__ xin, const int* __restrict__ off,
    const int* __restrict__ nbr, const unsigned short* __restrict__ WaT,
    const float* __restrict__ ba, const unsigned short* __restrict__ WbT,
    const float* __restrict__ bb, void* __restrict__ outp, int n_rows) {
    constexpr int SA = DIN + 16;  // padded LDS row (bf16 elements)
    constexpr int SH = DH + 16;
    __shared__ unsigned short tA[64 * SA];
    __shared__ unsigned short hidA[64 * SH];

    const int tid = threadIdx.x;
    const int row0 = blockIdx.x * 64;
    const int c = tid & 15;  // lane-within-node (16 lanes/node)

    // ---- Gather phase: aggregate 64 nodes into tA ----
#pragma unroll
    for (int g = 0; g < 4; ++g) {
        const int lrow = g * 16 + (tid >> 4);
        const int node = row0 + lrow;
        if (DIN == 64) {
            const uint2* xr = (const uint2*)xin;
            uint2 o = {0u, 0u};
            if (node < n_rows) {
                const uint2 a = xr[(size_t)node * 16 + c];
                float f0 = blo(a.x), f1 = bhi(a.x);
                float f2 = blo(a.y), f3 = bhi(a.y);
                const int lo = off[node], hi = off[node + 1];
                for (int j = lo; j < hi; ++j) {
                    const uint2 v = xr[(size_t)nbr[j] * 16 + c];
                    f0 += blo(v.x); f1 += bhi(v.x);
                    f2 += blo(v.y); f3 += bhi(v.y);
                }
                o.x = pk(f0, f1);
                o.y = pk(f2, f3);
            }
            *(uint2*)&tA[lrow * SA + c * 4] = o;
        } else {
            const uint4* xr = (const uint4*)xin;
            uint4 o = {0u, 0u, 0u, 0u};
            if (node < n_rows) {
                const uint4 a = xr[(size_t)node * 16 + c];
                float f0 = blo(a.x), f1 = bhi(a.x);
                float f2 = blo(a.y), f3 = bhi(a.y);
                float f4 = blo(a.z), f5 = bhi(a.z);
                float f6 = blo(a.w), f7 = bhi(a.w);
                const int lo = off[node], hi = off[node + 1];
                for (int j = lo; j < hi; ++j) {
                    const uint4 v = xr[(size_t)nbr[j] * 16 + c];
                    f0 += blo(v.x); f1 += bhi(v.x);
                    f2 += blo(v.y); f3 += bhi(v.y);
                    f4 += blo(v.z); f5 += bhi(v.z);
                    f6 += blo(v.w); f7 += bhi(v.w);
                }
                o.x = pk(f0, f1); o.y = pk(f2, f3);
                o.z = pk(f4, f5); o.w = pk(f6, f7);
            }
            *(uint4*)&tA[lrow * SA + c * 8] = o;
        }
    }
    __syncthreads();

    const int lane = tid & 63;
    const int wv = tid >> 6;
    const int quad = lane >> 4;
    const int l16 = lane & 15;
    const int m0 = wv * 16;

    // ---- Phase 1: hid = relu(T @ Wa + ba) ----
    short8 a1[DIN / 32];
#pragma unroll
    for (int kk = 0; kk < DIN / 32; ++kk)
        a1[kk] = *(const short8*)&tA[(m0 + l16) * SA + kk * 32 + quad * 8];
#pragma unroll
    for (int nt = 0; nt < DH / 16; ++nt) {
        floatx4 acc = {0.f, 0.f, 0.f, 0.f};
#pragma unroll
        for (int kk = 0; kk < DIN / 32; ++kk) {
            short8 b =
                *(const short8*)&WaT[(nt * 16 + l16) * DIN + kk * 32 + quad * 8];
            acc = __builtin_amdgcn_mfma_f32_16x16x32_bf16(a1[kk], b, acc, 0, 0, 0);
        }
        const float bias = ba[nt * 16 + l16];
#pragma unroll
        for (int r = 0; r < 4; ++r) {
            const float v = fmaxf(acc[r] + bias, 0.f);
            hidA[(m0 + quad * 4 + r) * SH + nt * 16 + l16] = f2b(v);
        }
    }

    // ---- Phase 2: out = relu(hid @ Wb + bb) ----  (same-wave strip only)
    short8 a2[DH / 32];
#pragma unroll
    for (int kk = 0; kk < DH / 32; ++kk)
        a2[kk] = *(const short8*)&hidA[(m0 + l16) * SH + kk * 32 + quad * 8];
#pragma unroll
    for (int nt = 0; nt < DOUT / 16; ++nt) {
        floatx4 acc = {0.f, 0.f, 0.f, 0.f};
#pragma unroll
        for (int kk = 0; kk < DH / 32; ++kk) {
            short8 b =
                *(const short8*)&WbT[(nt * 16 + l16) * DH + kk * 32 + quad * 8];
            acc = __builtin_amdgcn_mfma_f32_16x16x32_bf16(a2[kk], b, acc, 0, 0, 0);
        }
        const float bias = bb[nt * 16 + l16];
#pragma unroll
        for (int r = 0; r < 4; ++r) {
            const float v = fmaxf(acc[r] + bias, 0.f);
            const int grow = row0 + m0 + quad * 4 + r;
            if (grow < n_rows) {
                if (OUT_BF16)
                    ((unsigned short*)outp)[(size_t)grow * DOUT + nt * 16 + l16] =
                        f2b(v);
                else
                    ((float*)outp)[(size_t)grow * DOUT + nt * 16 + l16] = v;
            }
        }
    }
}

extern "C" void kernel_launch(void* const* d_in, const int* in_sizes, int n_in,
                              void* d_out, int out_size, void* d_ws,
                              size_t ws_size, hipStream_t stream) {
    const float* x   = (const float*)d_in[0];
    const int*   ei  = (const int*)d_in[1];  // [2, N_EDGES] int32
    const float* W1a = (const float*)d_in[2];
    const float* b1a = (const float*)d_in[3];
    const float* W1b = (const float*)d_in[4];
    const float* b1b = (const float*)d_in[5];
    const float* W2a = (const float*)d_in[6];
    const float* b2a = (const float*)d_in[7];
    const float* W2b = (const float*)d_in[8];
    const float* b2b = (const float*)d_in[9];
    float* out = (float*)d_out;

    const int* src = ei;
    const int* dst = ei + N_EDGES;

    // Workspace: bf16 xb[N,64] | bf16 h[N,128] | bf16 weightsT | int CSR
    unsigned short* xb = (unsigned short*)d_ws;
    unsigned short* h  = xb + (size_t)N_NODES * 64;
    unsigned short* W1aT = h + (size_t)N_NODES * 128;
    unsigned short* W1bT = W1aT + 8192;
    unsigned short* W2aT = W1bT + 16384;
    unsigned short* W2bT = W2aT + 16384;
    int* deg    = (int*)(W2bT + 8192);
    int* off    = deg + N_NODES;
    int* cursor = off + N_NODES + 1;
    int* nbr    = cursor + N_NODES;
    int* bsum   = nbr + N_EDGES;

    constexpr int NB = (N_NODES + 1023) / 1024;  // 49 scan blocks

    // ---- CSR build ----
    hipMemsetAsync(deg, 0, N_NODES * sizeof(int), stream);
    hist_kernel<<<(N_EDGES + 255) / 256, 256, 0, stream>>>(dst, deg, N_EDGES);
    scanA_kernel<<<NB, 1024, 0, stream>>>(deg, bsum, N_NODES);
    scanB_kernel<<<1, 64, 0, stream>>>(bsum, NB);
    scanC_kernel<<<NB, 1024, 0, stream>>>(deg, bsum, off, cursor, N_NODES);
    fill_kernel<<<(N_EDGES + 255) / 256, 256, 0, stream>>>(src, dst, cursor,
                                                           nbr, N_EDGES);
    prep_weights_kernel<<<192, 256, 0, stream>>>(W1a, W1b, W2a, W2b, W1aT,
                                                 W1bT, W2aT, W2bT);
    convert_x_kernel<<<(N_NODES * 16 + 255) / 256, 256, 0, stream>>>(
        x, xb, N_NODES * 16);

    // ---- Layer 1 (fused gather + MLP): h = mlp1(xb + agg(xb)) ----
    gin_fused_kernel<64, 128, 128, true>
        <<<(N_NODES + 63) / 64, 256, 0, stream>>>(xb, off, nbr, W1aT, b1a,
                                                  W1bT, b1b, h, N_NODES);

    // ---- Layer 2 (fused gather + MLP): out = mlp2(h + agg(h)) ----
    gin_fused_kernel<128, 128, 64, false>
        <<<(N_NODES + 63) / 64, 256, 0, stream>>>(h, off, nbr, W2aT, b2a,
                                                  W2bT, b2b, out, N_NODES);
}

// Round 6
// 271.198 us; speedup vs baseline: 1.2379x; 1.2379x over previous
//
#include <hip/hip_runtime.h>

#define N_NODES 50000
#define N_EDGES 800000

typedef __attribute__((ext_vector_type(8))) short short8;
typedef __attribute__((ext_vector_type(4))) float floatx4;

// float -> bf16 bits, round-to-nearest-even
static __device__ __forceinline__ unsigned short f2b(float f) {
    unsigned int u = __float_as_uint(f);
    unsigned int r = u + 0x7fffu + ((u >> 16) & 1u);
    return (unsigned short)(r >> 16);
}
static __device__ __forceinline__ unsigned int pk(float a, float b) {
    return (unsigned)f2b(a) | ((unsigned)f2b(b) << 16);
}
static __device__ __forceinline__ float blo(unsigned int u) {
    return __uint_as_float(u << 16);
}
static __device__ __forceinline__ float bhi(unsigned int u) {
    return __uint_as_float(u & 0xffff0000u);
}

// ---------------------------------------------------------------------------
// CSR build: histogram -> 3-phase parallel exclusive scan -> fill (ushort).
// ---------------------------------------------------------------------------
__global__ void hist_kernel(const int* __restrict__ dst, int* __restrict__ deg,
                            int n) {
    int i = blockIdx.x * blockDim.x + threadIdx.x;
    if (i < n) atomicAdd(&deg[dst[i]], 1);
}

__global__ __launch_bounds__(1024) void scanA_kernel(
    const int* __restrict__ deg, int* __restrict__ bsum, int n) {
    __shared__ int s[1024];
    const int tid = threadIdx.x;
    int i = blockIdx.x * 1024 + tid;
    s[tid] = (i < n) ? deg[i] : 0;
    __syncthreads();
    for (int d = 512; d > 0; d >>= 1) {
        if (tid < d) s[tid] += s[tid + d];
        __syncthreads();
    }
    if (tid == 0) bsum[blockIdx.x] = s[0];
}

__global__ __launch_bounds__(64) void scanB_kernel(int* __restrict__ bsum,
                                                   int nb) {
    const int tid = threadIdx.x;
    int v = (tid < nb) ? bsum[tid] : 0;
    for (int d = 1; d < 64; d <<= 1) {
        int t = __shfl_up(v, d, 64);
        if (tid >= d) v += t;
    }
    int excl = __shfl_up(v, 1, 64);
    if (tid == 0) excl = 0;
    if (tid < nb) bsum[tid] = excl;
}

__global__ __launch_bounds__(1024) void scanC_kernel(
    const int* __restrict__ deg, const int* __restrict__ bpref,
    int* __restrict__ off, int* __restrict__ cursor, int n) {
    __shared__ int s[1024];
    const int tid = threadIdx.x;
    const int i = blockIdx.x * 1024 + tid;
    const int v = (i < n) ? deg[i] : 0;
    s[tid] = v;
    __syncthreads();
    for (int d = 1; d < 1024; d <<= 1) {
        int t = (tid >= d) ? s[tid - d] : 0;
        __syncthreads();
        s[tid] += t;
        __syncthreads();
    }
    const int excl = s[tid] - v + bpref[blockIdx.x];
    if (i < n) {
        off[i] = excl;
        cursor[i] = excl;
        if (i == n - 1) off[n] = excl + v;
    }
}

// nbr as ushort (N_NODES < 65536): halves the scattered-store traffic.
__global__ void fill_kernel(const int* __restrict__ src,
                            const int* __restrict__ dst,
                            int* __restrict__ cursor,
                            unsigned short* __restrict__ nbr, int n) {
    int i = blockIdx.x * blockDim.x + threadIdx.x;
    if (i < n) {
        int pos = atomicAdd(&cursor[dst[i]], 1);
        nbr[pos] = (unsigned short)src[i];
    }
}

// ---------------------------------------------------------------------------
// Weight prep: transpose to [N][K] row-major bf16 (one contiguous 16B load
// per MFMA B-fragment lane).
// ---------------------------------------------------------------------------
__global__ __launch_bounds__(256) void prep_weights_kernel(
    const float* __restrict__ W1a, const float* __restrict__ W1b,
    const float* __restrict__ W2a, const float* __restrict__ W2b,
    unsigned short* __restrict__ W1aT, unsigned short* __restrict__ W1bT,
    unsigned short* __restrict__ W2aT, unsigned short* __restrict__ W2bT) {
    int i = blockIdx.x * 256 + threadIdx.x;
    if (i < 8192) {                       // W1a [64][128] -> [128][64]
        int n = i >> 6, k = i & 63;
        W1aT[i] = f2b(W1a[k * 128 + n]);
    } else if (i < 24576) {               // W1b [128][128] -> [128][128]
        int j = i - 8192, n = j >> 7, k = j & 127;
        W1bT[j] = f2b(W1b[k * 128 + n]);
    } else if (i < 40960) {               // W2a [128][128] -> [128][128]
        int j = i - 24576, n = j >> 7, k = j & 127;
        W2aT[j] = f2b(W2a[k * 128 + n]);
    } else if (i < 49152) {               // W2b [128][64] -> [64][128]
        int j = i - 40960, n = j >> 7, k = j & 127;
        W2bT[j] = f2b(W2b[k * 64 + n]);
    }
}

// x fp32 [N][64] -> bf16 xb (halves gather1's random-row footprint)
__global__ __launch_bounds__(256) void convert_x_kernel(
    const float* __restrict__ x, unsigned short* __restrict__ xb, int n4) {
    int i = blockIdx.x * 256 + threadIdx.x;
    if (i < n4) {
        float4 v = ((const float4*)x)[i];
        uint2 o;
        o.x = pk(v.x, v.y);
        o.y = pk(v.z, v.w);
        ((uint2*)xb)[i] = o;
    }
}

// ---------------------------------------------------------------------------
// Gather (d=64 bf16): t1 = bf16(x_i + sum_nbr x_j). 16 lanes/node, 8B/lane.
// Neighbor loop unrolled x4 -> 4 independent row loads in flight per node;
// no LDS, low VGPR -> full occupancy -> latency hidden.
// ---------------------------------------------------------------------------
__global__ __launch_bounds__(256) void gather1_kernel(
    const unsigned short* __restrict__ xb, const int* __restrict__ off,
    const unsigned short* __restrict__ nbr, unsigned short* __restrict__ t1,
    int n_nodes) {
    const int tid = threadIdx.x;
    const int node = blockIdx.x * 16 + (tid >> 4);
    const int c = tid & 15;
    if (node >= n_nodes) return;
    const uint2* xr = (const uint2*)xb;
    const uint2 a = xr[(size_t)node * 16 + c];
    float f0 = blo(a.x), f1 = bhi(a.x), f2 = blo(a.y), f3 = bhi(a.y);
    const int lo = off[node], hi = off[node + 1];
    int j = lo;
    for (; j + 4 <= hi; j += 4) {
        const int s0 = nbr[j], s1 = nbr[j + 1], s2 = nbr[j + 2],
                  s3 = nbr[j + 3];
        const uint2 v0 = xr[(size_t)s0 * 16 + c];
        const uint2 v1 = xr[(size_t)s1 * 16 + c];
        const uint2 v2 = xr[(size_t)s2 * 16 + c];
        const uint2 v3 = xr[(size_t)s3 * 16 + c];
        f0 += (blo(v0.x) + blo(v1.x)) + (blo(v2.x) + blo(v3.x));
        f1 += (bhi(v0.x) + bhi(v1.x)) + (bhi(v2.x) + bhi(v3.x));
        f2 += (blo(v0.y) + blo(v1.y)) + (blo(v2.y) + blo(v3.y));
        f3 += (bhi(v0.y) + bhi(v1.y)) + (bhi(v2.y) + bhi(v3.y));
    }
    for (; j < hi; ++j) {
        const uint2 v = xr[(size_t)nbr[j] * 16 + c];
        f0 += blo(v.x); f1 += bhi(v.x);
        f2 += blo(v.y); f3 += bhi(v.y);
    }
    uint2 o;
    o.x = pk(f0, f1);
    o.y = pk(f2, f3);
    ((uint2*)t1)[(size_t)node * 16 + c] = o;
}

// Gather (d=128 bf16): 16 lanes/node, 16B/lane, unrolled x4.
__global__ __launch_bounds__(256) void gather2_kernel(
    const unsigned short* __restrict__ h, const int* __restrict__ off,
    const unsigned short* __restrict__ nbr, unsigned short* __restrict__ t2,
    int n_nodes) {
    const int tid = threadIdx.x;
    const int node = blockIdx.x * 16 + (tid >> 4);
    const int c = tid & 15;
    if (node >= n_nodes) return;
    const uint4* hr = (const uint4*)h;
    const uint4 a = hr[(size_t)node * 16 + c];
    float f0 = blo(a.x), f1 = bhi(a.x), f2 = blo(a.y), f3 = bhi(a.y);
    float f4 = blo(a.z), f5 = bhi(a.z), f6 = blo(a.w), f7 = bhi(a.w);
    const int lo = off[node], hi = off[node + 1];
    int j = lo;
    for (; j + 4 <= hi; j += 4) {
        const int s0 = nbr[j], s1 = nbr[j + 1], s2 = nbr[j + 2],
                  s3 = nbr[j + 3];
        const uint4 v0 = hr[(size_t)s0 * 16 + c];
        const uint4 v1 = hr[(size_t)s1 * 16 + c];
        const uint4 v2 = hr[(size_t)s2 * 16 + c];
        const uint4 v3 = hr[(size_t)s3 * 16 + c];
        f0 += (blo(v0.x) + blo(v1.x)) + (blo(v2.x) + blo(v3.x));
        f1 += (bhi(v0.x) + bhi(v1.x)) + (bhi(v2.x) + bhi(v3.x));
        f2 += (blo(v0.y) + blo(v1.y)) + (blo(v2.y) + blo(v3.y));
        f3 += (bhi(v0.y) + bhi(v1.y)) + (bhi(v2.y) + bhi(v3.y));
        f4 += (blo(v0.z) + blo(v1.z)) + (blo(v2.z) + blo(v3.z));
        f5 += (bhi(v0.z) + bhi(v1.z)) + (bhi(v2.z) + bhi(v3.z));
        f6 += (blo(v0.w) + blo(v1.w)) + (blo(v2.w) + blo(v3.w));
        f7 += (bhi(v0.w) + bhi(v1.w)) + (bhi(v2.w) + bhi(v3.w));
    }
    for (; j < hi; ++j) {
        const uint4 v = hr[(size_t)nbr[j] * 16 + c];
        f0 += blo(v.x); f1 += bhi(v.x); f2 += blo(v.y); f3 += bhi(v.y);
        f4 += blo(v.z); f5 += bhi(v.z); f6 += blo(v.w); f7 += bhi(v.w);
    }
    uint4 o;
    o.x = pk(f0, f1); o.y = pk(f2, f3);
    o.z = pk(f4, f5); o.w = pk(f6, f7);
    ((uint4*)t2)[(size_t)node * 16 + c] = o;
}

// ---------------------------------------------------------------------------
// 2-layer MLP via MFMA 16x16x32 bf16, fp32 accumulate (round-4 verified).
//   out = relu( relu(T @ Wa + ba) @ Wb + bb )
// Block = 256 thr (4 waves), 64 rows; wave w owns rows [w*16, w*16+16).
// C/D layout: col=lane&15, row=quad*4+reg. No barrier between phases (each
// wave reads back only its own hidden strip).
// ---------------------------------------------------------------------------
template <int DIN, int DH, int DOUT, bool OUT_BF16>
__global__ __launch_bounds__(256) void mlp_mfma_kernel(
    const unsigned short* __restrict__ t, const unsigned short* __restrict__ WaT,
    const float* __restrict__ ba, const unsigned short* __restrict__ WbT,
    const float* __restrict__ bb, void* __restrict__ outp, int n_rows) {
    constexpr int SA = DIN + 16;
    constexpr int SH = DH + 16;
    __shared__ unsigned short tA[64 * SA];
    __shared__ unsigned short hidA[64 * SH];

    const int tid = threadIdx.x;
    const int row0 = blockIdx.x * 64;

    constexpr int CHUNKS = 64 * DIN / 8;
    const uint4* tg = (const uint4*)t;
    for (int i = tid; i < CHUNKS; i += 256) {
        const int row = i / (DIN / 8);
        const int cb = i % (DIN / 8);
        uint4 v = {0u, 0u, 0u, 0u};
        const int gr = row0 + row;
        if (gr < n_rows) v = tg[(size_t)gr * (DIN / 8) + cb];
        *(uint4*)&tA[row * SA + cb * 8] = v;
    }
    __syncthreads();

    const int lane = tid & 63;
    const int wv = tid >> 6;
    const int quad = lane >> 4;
    const int l16 = lane & 15;
    const int m0 = wv * 16;

    short8 a1[DIN / 32];
#pragma unroll
    for (int kk = 0; kk < DIN / 32; ++kk)
        a1[kk] = *(const short8*)&tA[(m0 + l16) * SA + kk * 32 + quad * 8];
#pragma unroll
    for (int nt = 0; nt < DH / 16; ++nt) {
        floatx4 acc = {0.f, 0.f, 0.f, 0.f};
#pragma unroll
        for (int kk = 0; kk < DIN / 32; ++kk) {
            short8 b =
                *(const short8*)&WaT[(nt * 16 + l16) * DIN + kk * 32 + quad * 8];
            acc = __builtin_amdgcn_mfma_f32_16x16x32_bf16(a1[kk], b, acc, 0, 0, 0);
        }
        const float bias = ba[nt * 16 + l16];
#pragma unroll
        for (int r = 0; r < 4; ++r) {
            const float v = fmaxf(acc[r] + bias, 0.f);
            hidA[(m0 + quad * 4 + r) * SH + nt * 16 + l16] = f2b(v);
        }
    }

    short8 a2[DH / 32];
#pragma unroll
    for (int kk = 0; kk < DH / 32; ++kk)
        a2[kk] = *(const short8*)&hidA[(m0 + l16) * SH + kk * 32 + quad * 8];
#pragma unroll
    for (int nt = 0; nt < DOUT / 16; ++nt) {
        floatx4 acc = {0.f, 0.f, 0.f, 0.f};
#pragma unroll
        for (int kk = 0; kk < DH / 32; ++kk) {
            short8 b =
                *(const short8*)&WbT[(nt * 16 + l16) * DH + kk * 32 + quad * 8];
            acc = __builtin_amdgcn_mfma_f32_16x16x32_bf16(a2[kk], b, acc, 0, 0, 0);
        }
        const float bias = bb[nt * 16 + l16];
#pragma unroll
        for (int r = 0; r < 4; ++r) {
            const float v = fmaxf(acc[r] + bias, 0.f);
            const int grow = row0 + m0 + quad * 4 + r;
            if (grow < n_rows) {
                if (OUT_BF16)
                    ((unsigned short*)outp)[(size_t)grow * DOUT + nt * 16 + l16] =
                        f2b(v);
                else
                    ((float*)outp)[(size_t)grow * DOUT + nt * 16 + l16] = v;
            }
        }
    }
}

extern "C" void kernel_launch(void* const* d_in, const int* in_sizes, int n_in,
                              void* d_out, int out_size, void* d_ws,
                              size_t ws_size, hipStream_t stream) {
    const float* x   = (const float*)d_in[0];
    const int*   ei  = (const int*)d_in[1];  // [2, N_EDGES] int32
    const float* W1a = (const float*)d_in[2];
    const float* b1a = (const float*)d_in[3];
    const float* W1b = (const float*)d_in[4];
    const float* b1b = (const float*)d_in[5];
    const float* W2a = (const float*)d_in[6];
    const float* b2a = (const float*)d_in[7];
    const float* W2b = (const float*)d_in[8];
    const float* b2b = (const float*)d_in[9];
    float* out = (float*)d_out;

    const int* src = ei;
    const int* dst = ei + N_EDGES;

    // Workspace: bf16 xb[N,64] t1[N,64] h[N,128] t2[N,128] | bf16 weightsT |
    //            int deg/off/cursor/bsum | ushort nbr[E]
    unsigned short* xb = (unsigned short*)d_ws;
    unsigned short* t1 = xb + (size_t)N_NODES * 64;
    unsigned short* h  = t1 + (size_t)N_NODES * 64;
    unsigned short* t2 = h + (size_t)N_NODES * 128;
    unsigned short* W1aT = t2 + (size_t)N_NODES * 128;
    unsigned short* W1bT = W1aT + 8192;
    unsigned short* W2aT = W1bT + 16384;
    unsigned short* W2bT = W2aT + 16384;
    int* deg    = (int*)(W2bT + 8192);
    int* off    = deg + N_NODES;
    int* cursor = off + N_NODES + 1;
    int* bsum   = cursor + N_NODES;
    unsigned short* nbr = (unsigned short*)(bsum + 64);

    constexpr int NB = (N_NODES + 1023) / 1024;  // 49 scan blocks

    // ---- CSR build ----
    hipMemsetAsync(deg, 0, N_NODES * sizeof(int), stream);
    hist_kernel<<<(N_EDGES + 255) / 256, 256, 0, stream>>>(dst, deg, N_EDGES);
    scanA_kernel<<<NB, 1024, 0, stream>>>(deg, bsum, N_NODES);
    scanB_kernel<<<1, 64, 0, stream>>>(bsum, NB);
    scanC_kernel<<<NB, 1024, 0, stream>>>(deg, bsum, off, cursor, N_NODES);
    fill_kernel<<<(N_EDGES + 255) / 256, 256, 0, stream>>>(src, dst, cursor,
                                                           nbr, N_EDGES);
    prep_weights_kernel<<<192, 256, 0, stream>>>(W1a, W1b, W2a, W2b, W1aT,
                                                 W1bT, W2aT, W2bT);
    convert_x_kernel<<<(N_NODES * 16 + 255) / 256, 256, 0, stream>>>(
        x, xb, N_NODES * 16);

    // ---- Layer 1 ----
    gather1_kernel<<<(N_NODES + 15) / 16, 256, 0, stream>>>(xb, off, nbr, t1,
                                                            N_NODES);
    mlp_mfma_kernel<64, 128, 128, true>
        <<<(N_NODES + 63) / 64, 256, 0, stream>>>(t1, W1aT, b1a, W1bT, b1b, h,
                                                  N_NODES);

    // ---- Layer 2 ----
    gather2_kernel<<<(N_NODES + 15) / 16, 256, 0, stream>>>(h, off, nbr, t2,
                                                            N_NODES);
    mlp_mfma_kernel<128, 128, 64, false>
        <<<(N_NODES + 63) / 64, 256, 0, stream>>>(t2, W2aT, b2a, W2bT, b2b, out,
                                                  N_NODES);
}

// Round 7
// 267.110 us; speedup vs baseline: 1.2569x; 1.0153x over previous
//
#include <hip/hip_runtime.h>

#define N_NODES 50000
#define N_EDGES 800000
#define N_SG 8           // supergroups ~ XCDs
#define DST_PER_SG (N_NODES / N_SG)  // 6250

typedef __attribute__((ext_vector_type(8))) short short8;
typedef __attribute__((ext_vector_type(4))) float floatx4;

// float -> bf16 bits, round-to-nearest-even
static __device__ __forceinline__ unsigned short f2b(float f) {
    unsigned int u = __float_as_uint(f);
    unsigned int r = u + 0x7fffu + ((u >> 16) & 1u);
    return (unsigned short)(r >> 16);
}
static __device__ __forceinline__ unsigned int pk(float a, float b) {
    return (unsigned)f2b(a) | ((unsigned)f2b(b) << 16);
}
static __device__ __forceinline__ float blo(unsigned int u) {
    return __uint_as_float(u << 16);
}
static __device__ __forceinline__ float bhi(unsigned int u) {
    return __uint_as_float(u & 0xffff0000u);
}

// ---------------------------------------------------------------------------
// CSR build, XCD-partitioned. Supergroup g = blocks with blockIdx%8==g
// (workgroup->XCD round-robin heuristic; perf-only). Supergroup g owns
// dst range [g*6250,(g+1)*6250): its deg/cursor/nbr lines live in ONE
// XCD's L2 -> full-line writebacks once, no cross-XCD thrash.
// ---------------------------------------------------------------------------
__global__ __launch_bounds__(256) void hist_part_kernel(
    const int* __restrict__ dst, int* __restrict__ deg, int n) {
    const int sg = blockIdx.x & (N_SG - 1);
    const int cb = blockIdx.x >> 3;
    const int nchunks = gridDim.x >> 3;
    const int chunk = (n + nchunks - 1) / nchunks;
    const int lo = cb * chunk;
    const int hi = min(lo + chunk, n);
    const int dlo = sg * DST_PER_SG, dhi = dlo + DST_PER_SG;
    for (int e = lo + threadIdx.x; e < hi; e += 256) {
        const int d = dst[e];
        if (d >= dlo && d < dhi) atomicAdd(&deg[d], 1);
    }
}

__global__ __launch_bounds__(1024) void scanA_kernel(
    const int* __restrict__ deg, int* __restrict__ bsum, int n) {
    __shared__ int s[1024];
    const int tid = threadIdx.x;
    int i = blockIdx.x * 1024 + tid;
    s[tid] = (i < n) ? deg[i] : 0;
    __syncthreads();
    for (int d = 512; d > 0; d >>= 1) {
        if (tid < d) s[tid] += s[tid + d];
        __syncthreads();
    }
    if (tid == 0) bsum[blockIdx.x] = s[0];
}

// In-block exclusive scan + locally-computed block prefix (bsum has only
// 49 entries -> serial sum beats a separate scanB dispatch).
__global__ __launch_bounds__(1024) void scanC_kernel(
    const int* __restrict__ deg, const int* __restrict__ bsum,
    int* __restrict__ off, int* __restrict__ cursor, int n) {
    __shared__ int s[1024];
    __shared__ int bpref;
    const int tid = threadIdx.x;
    if (tid == 0) {
        int p = 0;
        for (int j = 0; j < blockIdx.x; ++j) p += bsum[j];
        bpref = p;
    }
    const int i = blockIdx.x * 1024 + tid;
    const int v = (i < n) ? deg[i] : 0;
    s[tid] = v;
    __syncthreads();
    for (int d = 1; d < 1024; d <<= 1) {
        int t = (tid >= d) ? s[tid - d] : 0;
        __syncthreads();
        s[tid] += t;
        __syncthreads();
    }
    const int excl = s[tid] - v + bpref;
    if (i < n) {
        off[i] = excl;
        cursor[i] = excl;
        if (i == n - 1) off[n] = excl + v;
    }
}

__global__ __launch_bounds__(256) void fill_part_kernel(
    const int* __restrict__ src, const int* __restrict__ dst,
    int* __restrict__ cursor, unsigned short* __restrict__ nbr, int n) {
    const int sg = blockIdx.x & (N_SG - 1);
    const int cb = blockIdx.x >> 3;
    const int nchunks = gridDim.x >> 3;
    const int chunk = (n + nchunks - 1) / nchunks;
    const int lo = cb * chunk;
    const int hi = min(lo + chunk, n);
    const int dlo = sg * DST_PER_SG, dhi = dlo + DST_PER_SG;
    for (int e = lo + threadIdx.x; e < hi; e += 256) {
        const int d = dst[e];
        if (d >= dlo && d < dhi) {
            int pos = atomicAdd(&cursor[d], 1);
            nbr[pos] = (unsigned short)src[e];
        }
    }
}

// ---------------------------------------------------------------------------
// Fused prep: weight transpose->bf16 [N][K] (one 16B load per MFMA B-frag
// lane) + x fp32->bf16 conversion. Independent elementwise work, one launch.
// ---------------------------------------------------------------------------
__global__ __launch_bounds__(256) void prep_kernel(
    const float* __restrict__ W1a, const float* __restrict__ W1b,
    const float* __restrict__ W2a, const float* __restrict__ W2b,
    const float* __restrict__ x, unsigned short* __restrict__ W1aT,
    unsigned short* __restrict__ W1bT, unsigned short* __restrict__ W2aT,
    unsigned short* __restrict__ W2bT, unsigned short* __restrict__ xb) {
    int i = blockIdx.x * 256 + threadIdx.x;
    if (i < 8192) {                       // W1a [64][128] -> [128][64]
        int n = i >> 6, k = i & 63;
        W1aT[i] = f2b(W1a[k * 128 + n]);
    } else if (i < 24576) {               // W1b [128][128] -> [128][128]
        int j = i - 8192, n = j >> 7, k = j & 127;
        W1bT[j] = f2b(W1b[k * 128 + n]);
    } else if (i < 40960) {               // W2a [128][128] -> [128][128]
        int j = i - 24576, n = j >> 7, k = j & 127;
        W2aT[j] = f2b(W2a[k * 128 + n]);
    } else if (i < 49152) {               // W2b [128][64] -> [64][128]
        int j = i - 40960, n = j >> 7, k = j & 127;
        W2bT[j] = f2b(W2b[k * 64 + n]);
    } else {                              // x convert: float4 -> 4x bf16
        int j = i - 49152;
        if (j < N_NODES * 16) {
            float4 v = ((const float4*)x)[j];
            uint2 o;
            o.x = pk(v.x, v.y);
            o.y = pk(v.z, v.w);
            ((uint2*)xb)[j] = o;
        }
    }
}

// ---------------------------------------------------------------------------
// Gather (d=64 bf16): t1 = bf16(x_i + sum_nbr x_j). 16 lanes/node, 8B/lane,
// neighbor loop unrolled x4 (4 independent row loads in flight), no LDS ->
// full occupancy -> latency hidden.
// ---------------------------------------------------------------------------
__global__ __launch_bounds__(256) void gather1_kernel(
    const unsigned short* __restrict__ xb, const int* __restrict__ off,
    const unsigned short* __restrict__ nbr, unsigned short* __restrict__ t1,
    int n_nodes) {
    const int tid = threadIdx.x;
    const int node = blockIdx.x * 16 + (tid >> 4);
    const int c = tid & 15;
    if (node >= n_nodes) return;
    const uint2* xr = (const uint2*)xb;
    const uint2 a = xr[(size_t)node * 16 + c];
    float f0 = blo(a.x), f1 = bhi(a.x), f2 = blo(a.y), f3 = bhi(a.y);
    const int lo = off[node], hi = off[node + 1];
    int j = lo;
    for (; j + 4 <= hi; j += 4) {
        const int s0 = nbr[j], s1 = nbr[j + 1], s2 = nbr[j + 2],
                  s3 = nbr[j + 3];
        const uint2 v0 = xr[(size_t)s0 * 16 + c];
        const uint2 v1 = xr[(size_t)s1 * 16 + c];
        const uint2 v2 = xr[(size_t)s2 * 16 + c];
        const uint2 v3 = xr[(size_t)s3 * 16 + c];
        f0 += (blo(v0.x) + blo(v1.x)) + (blo(v2.x) + blo(v3.x));
        f1 += (bhi(v0.x) + bhi(v1.x)) + (bhi(v2.x) + bhi(v3.x));
        f2 += (blo(v0.y) + blo(v1.y)) + (blo(v2.y) + blo(v3.y));
        f3 += (bhi(v0.y) + bhi(v1.y)) + (bhi(v2.y) + bhi(v3.y));
    }
    for (; j < hi; ++j) {
        const uint2 v = xr[(size_t)nbr[j] * 16 + c];
        f0 += blo(v.x); f1 += bhi(v.x);
        f2 += blo(v.y); f3 += bhi(v.y);
    }
    uint2 o;
    o.x = pk(f0, f1);
    o.y = pk(f2, f3);
    ((uint2*)t1)[(size_t)node * 16 + c] = o;
}

// Gather (d=128 bf16): 16 lanes/node, 16B/lane, unrolled x4.
__global__ __launch_bounds__(256) void gather2_kernel(
    const unsigned short* __restrict__ h, const int* __restrict__ off,
    const unsigned short* __restrict__ nbr, unsigned short* __restrict__ t2,
    int n_nodes) {
    const int tid = threadIdx.x;
    const int node = blockIdx.x * 16 + (tid >> 4);
    const int c = tid & 15;
    if (node >= n_nodes) return;
    const uint4* hr = (const uint4*)h;
    const uint4 a = hr[(size_t)node * 16 + c];
    float f0 = blo(a.x), f1 = bhi(a.x), f2 = blo(a.y), f3 = bhi(a.y);
    float f4 = blo(a.z), f5 = bhi(a.z), f6 = blo(a.w), f7 = bhi(a.w);
    const int lo = off[node], hi = off[node + 1];
    int j = lo;
    for (; j + 4 <= hi; j += 4) {
        const int s0 = nbr[j], s1 = nbr[j + 1], s2 = nbr[j + 2],
                  s3 = nbr[j + 3];
        const uint4 v0 = hr[(size_t)s0 * 16 + c];
        const uint4 v1 = hr[(size_t)s1 * 16 + c];
        const uint4 v2 = hr[(size_t)s2 * 16 + c];
        const uint4 v3 = hr[(size_t)s3 * 16 + c];
        f0 += (blo(v0.x) + blo(v1.x)) + (blo(v2.x) + blo(v3.x));
        f1 += (bhi(v0.x) + bhi(v1.x)) + (bhi(v2.x) + bhi(v3.x));
        f2 += (blo(v0.y) + blo(v1.y)) + (blo(v2.y) + blo(v3.y));
        f3 += (bhi(v0.y) + bhi(v1.y)) + (bhi(v2.y) + bhi(v3.y));
        f4 += (blo(v0.z) + blo(v1.z)) + (blo(v2.z) + blo(v3.z));
        f5 += (bhi(v0.z) + bhi(v1.z)) + (bhi(v2.z) + bhi(v3.z));
        f6 += (blo(v0.w) + blo(v1.w)) + (blo(v2.w) + blo(v3.w));
        f7 += (bhi(v0.w) + bhi(v1.w)) + (bhi(v2.w) + bhi(v3.w));
    }
    for (; j < hi; ++j) {
        const uint4 v = hr[(size_t)nbr[j] * 16 + c];
        f0 += blo(v.x); f1 += bhi(v.x); f2 += blo(v.y); f3 += bhi(v.y);
        f4 += blo(v.z); f5 += bhi(v.z); f6 += blo(v.w); f7 += bhi(v.w);
    }
    uint4 o;
    o.x = pk(f0, f1); o.y = pk(f2, f3);
    o.z = pk(f4, f5); o.w = pk(f6, f7);
    ((uint4*)t2)[(size_t)node * 16 + c] = o;
}

// ---------------------------------------------------------------------------
// 2-layer MLP via MFMA 16x16x32 bf16, fp32 accumulate (round-4 verified).
//   out = relu( relu(T @ Wa + ba) @ Wb + bb )
// Block = 256 thr (4 waves), 64 rows; wave w owns rows [w*16, w*16+16).
// C/D layout: col=lane&15, row=quad*4+reg. No barrier between phases (each
// wave reads back only its own hidden strip).
// ---------------------------------------------------------------------------
template <int DIN, int DH, int DOUT, bool OUT_BF16>
__global__ __launch_bounds__(256) void mlp_mfma_kernel(
    const unsigned short* __restrict__ t, const unsigned short* __restrict__ WaT,
    const float* __restrict__ ba, const unsigned short* __restrict__ WbT,
    const float* __restrict__ bb, void* __restrict__ outp, int n_rows) {
    constexpr int SA = DIN + 16;
    constexpr int SH = DH + 16;
    __shared__ unsigned short tA[64 * SA];
    __shared__ unsigned short hidA[64 * SH];

    const int tid = threadIdx.x;
    const int row0 = blockIdx.x * 64;

    constexpr int CHUNKS = 64 * DIN / 8;
    const uint4* tg = (const uint4*)t;
    for (int i = tid; i < CHUNKS; i += 256) {
        const int row = i / (DIN / 8);
        const int cb = i % (DIN / 8);
        uint4 v = {0u, 0u, 0u, 0u};
        const int gr = row0 + row;
        if (gr < n_rows) v = tg[(size_t)gr * (DIN / 8) + cb];
        *(uint4*)&tA[row * SA + cb * 8] = v;
    }
    __syncthreads();

    const int lane = tid & 63;
    const int wv = tid >> 6;
    const int quad = lane >> 4;
    const int l16 = lane & 15;
    const int m0 = wv * 16;

    short8 a1[DIN / 32];
#pragma unroll
    for (int kk = 0; kk < DIN / 32; ++kk)
        a1[kk] = *(const short8*)&tA[(m0 + l16) * SA + kk * 32 + quad * 8];
#pragma unroll
    for (int nt = 0; nt < DH / 16; ++nt) {
        floatx4 acc = {0.f, 0.f, 0.f, 0.f};
#pragma unroll
        for (int kk = 0; kk < DIN / 32; ++kk) {
            short8 b =
                *(const short8*)&WaT[(nt * 16 + l16) * DIN + kk * 32 + quad * 8];
            acc = __builtin_amdgcn_mfma_f32_16x16x32_bf16(a1[kk], b, acc, 0, 0, 0);
        }
        const float bias = ba[nt * 16 + l16];
#pragma unroll
        for (int r = 0; r < 4; ++r) {
            const float v = fmaxf(acc[r] + bias, 0.f);
            hidA[(m0 + quad * 4 + r) * SH + nt * 16 + l16] = f2b(v);
        }
    }

    short8 a2[DH / 32];
#pragma unroll
    for (int kk = 0; kk < DH / 32; ++kk)
        a2[kk] = *(const short8*)&hidA[(m0 + l16) * SH + kk * 32 + quad * 8];
#pragma unroll
    for (int nt = 0; nt < DOUT / 16; ++nt) {
        floatx4 acc = {0.f, 0.f, 0.f, 0.f};
#pragma unroll
        for (int kk = 0; kk < DH / 32; ++kk) {
            short8 b =
                *(const short8*)&WbT[(nt * 16 + l16) * DH + kk * 32 + quad * 8];
            acc = __builtin_amdgcn_mfma_f32_16x16x32_bf16(a2[kk], b, acc, 0, 0, 0);
        }
        const float bias = bb[nt * 16 + l16];
#pragma unroll
        for (int r = 0; r < 4; ++r) {
            const float v = fmaxf(acc[r] + bias, 0.f);
            const int grow = row0 + m0 + quad * 4 + r;
            if (grow < n_rows) {
                if (OUT_BF16)
                    ((unsigned short*)outp)[(size_t)grow * DOUT + nt * 16 + l16] =
                        f2b(v);
                else
                    ((float*)outp)[(size_t)grow * DOUT + nt * 16 + l16] = v;
            }
        }
    }
}

extern "C" void kernel_launch(void* const* d_in, const int* in_sizes, int n_in,
                              void* d_out, int out_size, void* d_ws,
                              size_t ws_size, hipStream_t stream) {
    const float* x   = (const float*)d_in[0];
    const int*   ei  = (const int*)d_in[1];  // [2, N_EDGES] int32
    const float* W1a = (const float*)d_in[2];
    const float* b1a = (const float*)d_in[3];
    const float* W1b = (const float*)d_in[4];
    const float* b1b = (const float*)d_in[5];
    const float* W2a = (const float*)d_in[6];
    const float* b2a = (const float*)d_in[7];
    const float* W2b = (const float*)d_in[8];
    const float* b2b = (const float*)d_in[9];
    float* out = (float*)d_out;

    const int* src = ei;
    const int* dst = ei + N_EDGES;

    // Workspace: bf16 xb[N,64] t1[N,64] h[N,128] t2[N,128] | bf16 weightsT |
    //            int deg/off/cursor/bsum | ushort nbr[E]
    unsigned short* xb = (unsigned short*)d_ws;
    unsigned short* t1 = xb + (size_t)N_NODES * 64;
    unsigned short* h  = t1 + (size_t)N_NODES * 64;
    unsigned short* t2 = h + (size_t)N_NODES * 128;
    unsigned short* W1aT = t2 + (size_t)N_NODES * 128;
    unsigned short* W1bT = W1aT + 8192;
    unsigned short* W2aT = W1bT + 16384;
    unsigned short* W2bT = W2aT + 16384;
    int* deg    = (int*)(W2bT + 8192);
    int* off    = deg + N_NODES;
    int* cursor = off + N_NODES + 1;
    int* bsum   = cursor + N_NODES;
    unsigned short* nbr = (unsigned short*)(bsum + 64);

    constexpr int NB = (N_NODES + 1023) / 1024;  // 49 scan blocks

    // ---- CSR build (XCD-partitioned hist/fill) ----
    hipMemsetAsync(deg, 0, N_NODES * sizeof(int), stream);
    hist_part_kernel<<<1024, 256, 0, stream>>>(dst, deg, N_EDGES);
    scanA_kernel<<<NB, 1024, 0, stream>>>(deg, bsum, N_NODES);
    scanC_kernel<<<NB, 1024, 0, stream>>>(deg, bsum, off, cursor, N_NODES);
    fill_part_kernel<<<1024, 256, 0, stream>>>(src, dst, cursor, nbr, N_EDGES);
    prep_kernel<<<(49152 + N_NODES * 16 + 255) / 256, 256, 0, stream>>>(
        W1a, W1b, W2a, W2b, x, W1aT, W1bT, W2aT, W2bT, xb);

    // ---- Layer 1 ----
    gather1_kernel<<<(N_NODES + 15) / 16, 256, 0, stream>>>(xb, off, nbr, t1,
                                                            N_NODES);
    mlp_mfma_kernel<64, 128, 128, true>
        <<<(N_NODES + 63) / 64, 256, 0, stream>>>(t1, W1aT, b1a, W1bT, b1b, h,
                                                  N_NODES);

    // ---- Layer 2 ----
    gather2_kernel<<<(N_NODES + 15) / 16, 256, 0, stream>>>(h, off, nbr, t2,
                                                            N_NODES);
    mlp_mfma_kernel<128, 128, 64, false>
        <<<(N_NODES + 63) / 64, 256, 0, stream>>>(t2, W2aT, b2a, W2bT, b2b, out,
                                                  N_NODES);
}

// Round 8
// 238.957 us; speedup vs baseline: 1.4049x; 1.1178x over previous
//
#include <hip/hip_runtime.h>

#define N_NODES 50000
#define N_EDGES 800000

typedef __attribute__((ext_vector_type(8))) short short8;
typedef __attribute__((ext_vector_type(4))) float floatx4;

// float -> bf16 bits, round-to-nearest-even
static __device__ __forceinline__ unsigned short f2b(float f) {
    unsigned int u = __float_as_uint(f);
    unsigned int r = u + 0x7fffu + ((u >> 16) & 1u);
    return (unsigned short)(r >> 16);
}
static __device__ __forceinline__ unsigned int pk(float a, float b) {
    return (unsigned)f2b(a) | ((unsigned)f2b(b) << 16);
}
static __device__ __forceinline__ float blo(unsigned int u) {
    return __uint_as_float(u << 16);
}
static __device__ __forceinline__ float bhi(unsigned int u) {
    return __uint_as_float(u & 0xffff0000u);
}

// ---------------------------------------------------------------------------
// CSR build. hist_rank: deg histogram AND per-edge rank in one pass — the
// atomicAdd return value is the edge's slot within its dst segment. fill is
// then atomic-free (no latency chain): pure coalesced loads + scattered store.
// ---------------------------------------------------------------------------
__global__ void hist_rank_kernel(const int* __restrict__ dst,
                                 int* __restrict__ deg, int* __restrict__ rank,
                                 int n) {
    int i = blockIdx.x * blockDim.x + threadIdx.x;
    if (i < n) rank[i] = atomicAdd(&deg[dst[i]], 1);
}

__global__ __launch_bounds__(1024) void scanA_kernel(
    const int* __restrict__ deg, int* __restrict__ bsum, int n) {
    __shared__ int s[1024];
    const int tid = threadIdx.x;
    int i = blockIdx.x * 1024 + tid;
    s[tid] = (i < n) ? deg[i] : 0;
    __syncthreads();
    for (int d = 512; d > 0; d >>= 1) {
        if (tid < d) s[tid] += s[tid + d];
        __syncthreads();
    }
    if (tid == 0) bsum[blockIdx.x] = s[0];
}

// In-block exclusive scan + serial 49-entry block prefix (cheaper than a
// separate scanB dispatch).
__global__ __launch_bounds__(1024) void scanC_kernel(
    const int* __restrict__ deg, const int* __restrict__ bsum,
    int* __restrict__ off, int n) {
    __shared__ int s[1024];
    __shared__ int bpref;
    const int tid = threadIdx.x;
    if (tid == 0) {
        int p = 0;
        for (int j = 0; j < blockIdx.x; ++j) p += bsum[j];
        bpref = p;
    }
    const int i = blockIdx.x * 1024 + tid;
    const int v = (i < n) ? deg[i] : 0;
    s[tid] = v;
    __syncthreads();
    for (int d = 1; d < 1024; d <<= 1) {
        int t = (tid >= d) ? s[tid - d] : 0;
        __syncthreads();
        s[tid] += t;
        __syncthreads();
    }
    const int excl = s[tid] - v + bpref;
    if (i < n) {
        off[i] = excl;
        if (i == n - 1) off[n] = excl + v;
    }
}

// Atomic-free fill: pos precomputed from off + rank. Fire-and-forget stores.
__global__ void fill_kernel(const int* __restrict__ src,
                            const int* __restrict__ dst,
                            const int* __restrict__ rank,
                            const int* __restrict__ off,
                            unsigned short* __restrict__ nbr, int n) {
    int i = blockIdx.x * blockDim.x + threadIdx.x;
    if (i < n) nbr[off[dst[i]] + rank[i]] = (unsigned short)src[i];
}

// ---------------------------------------------------------------------------
// Fused prep: weight transpose->bf16 [N][K] + x fp32->bf16 + deg zeroing
// (replaces a separate memset dispatch). All independent elementwise work.
// ---------------------------------------------------------------------------
__global__ __launch_bounds__(256) void prep_kernel(
    const float* __restrict__ W1a, const float* __restrict__ W1b,
    const float* __restrict__ W2a, const float* __restrict__ W2b,
    const float* __restrict__ x, unsigned short* __restrict__ W1aT,
    unsigned short* __restrict__ W1bT, unsigned short* __restrict__ W2aT,
    unsigned short* __restrict__ W2bT, unsigned short* __restrict__ xb,
    int* __restrict__ deg) {
    int i = blockIdx.x * 256 + threadIdx.x;
    if (i < 8192) {                       // W1a [64][128] -> [128][64]
        int n = i >> 6, k = i & 63;
        W1aT[i] = f2b(W1a[k * 128 + n]);
    } else if (i < 24576) {               // W1b [128][128] -> [128][128]
        int j = i - 8192, n = j >> 7, k = j & 127;
        W1bT[j] = f2b(W1b[k * 128 + n]);
    } else if (i < 40960) {               // W2a [128][128] -> [128][128]
        int j = i - 24576, n = j >> 7, k = j & 127;
        W2aT[j] = f2b(W2a[k * 128 + n]);
    } else if (i < 49152) {               // W2b [128][64] -> [64][128]
        int j = i - 40960, n = j >> 7, k = j & 127;
        W2bT[j] = f2b(W2b[k * 64 + n]);
    } else if (i < 49152 + N_NODES * 16) {  // x convert: float4 -> 4x bf16
        int j = i - 49152;
        float4 v = ((const float4*)x)[j];
        uint2 o;
        o.x = pk(v.x, v.y);
        o.y = pk(v.z, v.w);
        ((uint2*)xb)[j] = o;
    } else {                              // zero deg
        int j = i - (49152 + N_NODES * 16);
        if (j < N_NODES) deg[j] = 0;
    }
}

// ---------------------------------------------------------------------------
// Gather (d=64 bf16): t1 = bf16(x_i + sum_nbr x_j). 16 lanes/node, 8B/lane,
// neighbor loop unrolled x4 (4 independent row loads in flight), no LDS ->
// full occupancy -> latency hidden.
// ---------------------------------------------------------------------------
__global__ __launch_bounds__(256) void gather1_kernel(
    const unsigned short* __restrict__ xb, const int* __restrict__ off,
    const unsigned short* __restrict__ nbr, unsigned short* __restrict__ t1,
    int n_nodes) {
    const int tid = threadIdx.x;
    const int node = blockIdx.x * 16 + (tid >> 4);
    const int c = tid & 15;
    if (node >= n_nodes) return;
    const uint2* xr = (const uint2*)xb;
    const uint2 a = xr[(size_t)node * 16 + c];
    float f0 = blo(a.x), f1 = bhi(a.x), f2 = blo(a.y), f3 = bhi(a.y);
    const int lo = off[node], hi = off[node + 1];
    int j = lo;
    for (; j + 4 <= hi; j += 4) {
        const int s0 = nbr[j], s1 = nbr[j + 1], s2 = nbr[j + 2],
                  s3 = nbr[j + 3];
        const uint2 v0 = xr[(size_t)s0 * 16 + c];
        const uint2 v1 = xr[(size_t)s1 * 16 + c];
        const uint2 v2 = xr[(size_t)s2 * 16 + c];
        const uint2 v3 = xr[(size_t)s3 * 16 + c];
        f0 += (blo(v0.x) + blo(v1.x)) + (blo(v2.x) + blo(v3.x));
        f1 += (bhi(v0.x) + bhi(v1.x)) + (bhi(v2.x) + bhi(v3.x));
        f2 += (blo(v0.y) + blo(v1.y)) + (blo(v2.y) + blo(v3.y));
        f3 += (bhi(v0.y) + bhi(v1.y)) + (bhi(v2.y) + bhi(v3.y));
    }
    for (; j < hi; ++j) {
        const uint2 v = xr[(size_t)nbr[j] * 16 + c];
        f0 += blo(v.x); f1 += bhi(v.x);
        f2 += blo(v.y); f3 += bhi(v.y);
    }
    uint2 o;
    o.x = pk(f0, f1);
    o.y = pk(f2, f3);
    ((uint2*)t1)[(size_t)node * 16 + c] = o;
}

// Gather (d=128 bf16): 16 lanes/node, 16B/lane, unrolled x4.
__global__ __launch_bounds__(256) void gather2_kernel(
    const unsigned short* __restrict__ h, const int* __restrict__ off,
    const unsigned short* __restrict__ nbr, unsigned short* __restrict__ t2,
    int n_nodes) {
    const int tid = threadIdx.x;
    const int node = blockIdx.x * 16 + (tid >> 4);
    const int c = tid & 15;
    if (node >= n_nodes) return;
    const uint4* hr = (const uint4*)h;
    const uint4 a = hr[(size_t)node * 16 + c];
    float f0 = blo(a.x), f1 = bhi(a.x), f2 = blo(a.y), f3 = bhi(a.y);
    float f4 = blo(a.z), f5 = bhi(a.z), f6 = blo(a.w), f7 = bhi(a.w);
    const int lo = off[node], hi = off[node + 1];
    int j = lo;
    for (; j + 4 <= hi; j += 4) {
        const int s0 = nbr[j], s1 = nbr[j + 1], s2 = nbr[j + 2],
                  s3 = nbr[j + 3];
        const uint4 v0 = hr[(size_t)s0 * 16 + c];
        const uint4 v1 = hr[(size_t)s1 * 16 + c];
        const uint4 v2 = hr[(size_t)s2 * 16 + c];
        const uint4 v3 = hr[(size_t)s3 * 16 + c];
        f0 += (blo(v0.x) + blo(v1.x)) + (blo(v2.x) + blo(v3.x));
        f1 += (bhi(v0.x) + bhi(v1.x)) + (bhi(v2.x) + bhi(v3.x));
        f2 += (blo(v0.y) + blo(v1.y)) + (blo(v2.y) + blo(v3.y));
        f3 += (bhi(v0.y) + bhi(v1.y)) + (bhi(v2.y) + bhi(v3.y));
        f4 += (blo(v0.z) + blo(v1.z)) + (blo(v2.z) + blo(v3.z));
        f5 += (bhi(v0.z) + bhi(v1.z)) + (bhi(v2.z) + bhi(v3.z));
        f6 += (blo(v0.w) + blo(v1.w)) + (blo(v2.w) + blo(v3.w));
        f7 += (bhi(v0.w) + bhi(v1.w)) + (bhi(v2.w) + bhi(v3.w));
    }
    for (; j < hi; ++j) {
        const uint4 v = hr[(size_t)nbr[j] * 16 + c];
        f0 += blo(v.x); f1 += bhi(v.x); f2 += blo(v.y); f3 += bhi(v.y);
        f4 += blo(v.z); f5 += bhi(v.z); f6 += blo(v.w); f7 += bhi(v.w);
    }
    uint4 o;
    o.x = pk(f0, f1); o.y = pk(f2, f3);
    o.z = pk(f4, f5); o.w = pk(f6, f7);
    ((uint4*)t2)[(size_t)node * 16 + c] = o;
}

// ---------------------------------------------------------------------------
// 2-layer MLP via MFMA 16x16x32 bf16, fp32 accumulate (round-4 verified).
//   out = relu( relu(T @ Wa + ba) @ Wb + bb )
// Block = 256 thr (4 waves), 64 rows; wave w owns rows [w*16, w*16+16).
// C/D layout: col=lane&15, row=quad*4+reg. No barrier between phases (each
// wave reads back only its own hidden strip).
// ---------------------------------------------------------------------------
template <int DIN, int DH, int DOUT, bool OUT_BF16>
__global__ __launch_bounds__(256) void mlp_mfma_kernel(
    const unsigned short* __restrict__ t, const unsigned short* __restrict__ WaT,
    const float* __restrict__ ba, const unsigned short* __restrict__ WbT,
    const float* __restrict__ bb, void* __restrict__ outp, int n_rows) {
    constexpr int SA = DIN + 16;
    constexpr int SH = DH + 16;
    __shared__ unsigned short tA[64 * SA];
    __shared__ unsigned short hidA[64 * SH];

    const int tid = threadIdx.x;
    const int row0 = blockIdx.x * 64;

    constexpr int CHUNKS = 64 * DIN / 8;
    const uint4* tg = (const uint4*)t;
    for (int i = tid; i < CHUNKS; i += 256) {
        const int row = i / (DIN / 8);
        const int cb = i % (DIN / 8);
        uint4 v = {0u, 0u, 0u, 0u};
        const int gr = row0 + row;
        if (gr < n_rows) v = tg[(size_t)gr * (DIN / 8) + cb];
        *(uint4*)&tA[row * SA + cb * 8] = v;
    }
    __syncthreads();

    const int lane = tid & 63;
    const int wv = tid >> 6;
    const int quad = lane >> 4;
    const int l16 = lane & 15;
    const int m0 = wv * 16;

    short8 a1[DIN / 32];
#pragma unroll
    for (int kk = 0; kk < DIN / 32; ++kk)
        a1[kk] = *(const short8*)&tA[(m0 + l16) * SA + kk * 32 + quad * 8];
#pragma unroll
    for (int nt = 0; nt < DH / 16; ++nt) {
        floatx4 acc = {0.f, 0.f, 0.f, 0.f};
#pragma unroll
        for (int kk = 0; kk < DIN / 32; ++kk) {
            short8 b =
                *(const short8*)&WaT[(nt * 16 + l16) * DIN + kk * 32 + quad * 8];
            acc = __builtin_amdgcn_mfma_f32_16x16x32_bf16(a1[kk], b, acc, 0, 0, 0);
        }
        const float bias = ba[nt * 16 + l16];
#pragma unroll
        for (int r = 0; r < 4; ++r) {
            const float v = fmaxf(acc[r] + bias, 0.f);
            hidA[(m0 + quad * 4 + r) * SH + nt * 16 + l16] = f2b(v);
        }
    }

    short8 a2[DH / 32];
#pragma unroll
    for (int kk = 0; kk < DH / 32; ++kk)
        a2[kk] = *(const short8*)&hidA[(m0 + l16) * SH + kk * 32 + quad * 8];
#pragma unroll
    for (int nt = 0; nt < DOUT / 16; ++nt) {
        floatx4 acc = {0.f, 0.f, 0.f, 0.f};
#pragma unroll
        for (int kk = 0; kk < DH / 32; ++kk) {
            short8 b =
                *(const short8*)&WbT[(nt * 16 + l16) * DH + kk * 32 + quad * 8];
            acc = __builtin_amdgcn_mfma_f32_16x16x32_bf16(a2[kk], b, acc, 0, 0, 0);
        }
        const float bias = bb[nt * 16 + l16];
#pragma unroll
        for (int r = 0; r < 4; ++r) {
            const float v = fmaxf(acc[r] + bias, 0.f);
            const int grow = row0 + m0 + quad * 4 + r;
            if (grow < n_rows) {
                if (OUT_BF16)
                    ((unsigned short*)outp)[(size_t)grow * DOUT + nt * 16 + l16] =
                        f2b(v);
                else
                    ((float*)outp)[(size_t)grow * DOUT + nt * 16 + l16] = v;
            }
        }
    }
}

extern "C" void kernel_launch(void* const* d_in, const int* in_sizes, int n_in,
                              void* d_out, int out_size, void* d_ws,
                              size_t ws_size, hipStream_t stream) {
    const float* x   = (const float*)d_in[0];
    const int*   ei  = (const int*)d_in[1];  // [2, N_EDGES] int32
    const float* W1a = (const float*)d_in[2];
    const float* b1a = (const float*)d_in[3];
    const float* W1b = (const float*)d_in[4];
    const float* b1b = (const float*)d_in[5];
    const float* W2a = (const float*)d_in[6];
    const float* b2a = (const float*)d_in[7];
    const float* W2b = (const float*)d_in[8];
    const float* b2b = (const float*)d_in[9];
    float* out = (float*)d_out;

    const int* src = ei;
    const int* dst = ei + N_EDGES;

    // Workspace: bf16 xb[N,64] t1[N,64] h[N,128] t2[N,128] | bf16 weightsT |
    //            int deg/off/bsum/rank | ushort nbr[E]
    unsigned short* xb = (unsigned short*)d_ws;
    unsigned short* t1 = xb + (size_t)N_NODES * 64;
    unsigned short* h  = t1 + (size_t)N_NODES * 64;
    unsigned short* t2 = h + (size_t)N_NODES * 128;
    unsigned short* W1aT = t2 + (size_t)N_NODES * 128;
    unsigned short* W1bT = W1aT + 8192;
    unsigned short* W2aT = W1bT + 16384;
    unsigned short* W2bT = W2aT + 16384;
    int* deg  = (int*)(W2bT + 8192);
    int* off  = deg + N_NODES;
    int* bsum = off + N_NODES + 1;
    int* rank = bsum + 64;
    unsigned short* nbr = (unsigned short*)(rank + N_EDGES);

    constexpr int NB = (N_NODES + 1023) / 1024;  // 49 scan blocks
    constexpr int PREP_THREADS = 49152 + N_NODES * 16 + N_NODES;

    // ---- Prep (weights + x convert + deg zero) ----
    prep_kernel<<<(PREP_THREADS + 255) / 256, 256, 0, stream>>>(
        W1a, W1b, W2a, W2b, x, W1aT, W1bT, W2aT, W2bT, xb, deg);

    // ---- CSR build ----
    hist_rank_kernel<<<(N_EDGES + 255) / 256, 256, 0, stream>>>(dst, deg, rank,
                                                                N_EDGES);
    scanA_kernel<<<NB, 1024, 0, stream>>>(deg, bsum, N_NODES);
    scanC_kernel<<<NB, 1024, 0, stream>>>(deg, bsum, off, N_NODES);
    fill_kernel<<<(N_EDGES + 255) / 256, 256, 0, stream>>>(src, dst, rank, off,
                                                           nbr, N_EDGES);

    // ---- Layer 1 ----
    gather1_kernel<<<(N_NODES + 15) / 16, 256, 0, stream>>>(xb, off, nbr, t1,
                                                            N_NODES);
    mlp_mfma_kernel<64, 128, 128, true>
        <<<(N_NODES + 63) / 64, 256, 0, stream>>>(t1, W1aT, b1a, W1bT, b1b, h,
                                                  N_NODES);

    // ---- Layer 2 ----
    gather2_kernel<<<(N_NODES + 15) / 16, 256, 0, stream>>>(h, off, nbr, t2,
                                                            N_NODES);
    mlp_mfma_kernel<128, 128, 64, false>
        <<<(N_NODES + 63) / 64, 256, 0, stream>>>(t2, W2aT, b2a, W2bT, b2b, out,
                                                  N_NODES);
}